// Round 7
// baseline (46.842 us; speedup 1.0000x reference)
//
#include <hip/hip_runtime.h>
#include <hip/hip_bf16.h>
#include <math.h>

// SPP max-pool pyramid: x [B=32, H=64, W=64, C=512] f32 (NHWC, C innermost)
// scales (1,1),(2,2),(4,4),(8,8). Output row layout per batch (43520 floats):
//   [0,512)        : 1x1 scale
//   [512,2560)     : 2x2 scale, (i2*2+j2)*512 + c
//   [2560,10752)   : 4x4 scale, (i4*4+j4)*512 + c
//   [10752,43520)  : 8x8 scale, (i8*8+j8)*512 + c
// All bin sizes divide 64 evenly, so uniform bins (last-bin-extends is a no-op).
//
// SINGLE fused kernel. s8/s4 bins have a sole writer per channel range
// (plain stores). s2/s1 are published via device-scope integer atomics with
// the monotone-float encoding (fmax lattice: commutative, idempotent ->
// deterministic, replay-safe, no fences needed -- avoids R4's 47->131us
// agent-release L2-writeback disaster).

#define C_F4 128          // 512 channels / 4
#define ROW_OUT 43520     // 85 * 512
#define S8_OFF 10752
#define S4_OFF 2560
#define S2_OFF 512

typedef float vf4 __attribute__((ext_vector_type(4)));

static __device__ __forceinline__ vf4 vmax(vf4 a, vf4 b) {
    vf4 r;
    r.x = fmaxf(a.x, b.x);
    r.y = fmaxf(a.y, b.y);
    r.z = fmaxf(a.z, b.z);
    r.w = fmaxf(a.w, b.w);
    return r;
}

// fmax via native int atomics (monotone float-bit encoding, NaN-free input):
// v>=0: float bits as signed int are order-isomorphic above any stored value;
// v<0 : float bits as unsigned are reverse-ordered -> unsigned min.
// Any interleaving of these ops converges to the true float max.
static __device__ __forceinline__ void atomicFmax(float* p, float v) {
    if (v >= 0.0f) atomicMax(reinterpret_cast<int*>(p), __float_as_int(v));
    else           atomicMin(reinterpret_cast<unsigned int*>(p), __float_as_uint(v));
}

// One block per (b, i4, j4, chalf) = 1024 blocks x 256 threads (16 waves/CU;
// R6 showed the stream is latency-sensitive below this occupancy).
// Thread = (s in 0..3: 4-row band of the 16-row patch, c4i in 0..63: f4 slot
// within this block's 256-channel half).
__global__ __launch_bounds__(256) void spp_fused(const float* __restrict__ x,
                                                 float* __restrict__ out) {
    const int blk = blockIdx.x;            // 0..1023
    const int b     = blk >> 5;
    const int rem   = blk & 31;
    const int i4    = rem >> 3;
    const int j4    = (rem >> 1) & 3;
    const int chalf = rem & 1;
    const int tid = threadIdx.x;           // 0..255
    const int s   = tid >> 6;              // band 0..3 (rows 4s..4s+3)
    const int c4i = tid & 63;
    const int c4g = chalf * 64 + c4i;      // global f4 channel slot 0..127

    const int row0 = i4 * 16 + s * 4;
    const vf4* src = reinterpret_cast<const vf4*>(x)
                   + (size_t)((b * 64 + row0) * 64 + j4 * 16) * C_F4 + c4g;
    // vf4 strides: next col = 128, next row = 64*128 = 8192

    vf4 m0 = src[0];            // cols 0..7  (j8 = 2*j4)
    vf4 m1 = src[8 * 128];      // cols 8..15 (j8 = 2*j4+1)
    #pragma unroll
    for (int h = 0; h < 4; ++h) {
        #pragma unroll
        for (int w = 0; w < 8; ++w) {
            if (h == 0 && w == 0) continue;
            m0 = vmax(m0, src[h * 8192 + w * 128]);
            m1 = vmax(m1, src[h * 8192 + (w + 8) * 128]);
        }
    }

    __shared__ vf4 ls0[4][64];
    __shared__ vf4 ls1[4][64];
    ls0[s][c4i] = m0;
    ls1[s][c4i] = m1;
    __syncthreads();

    float* row = out + (size_t)b * ROW_OUT;
    if (s < 2) {
        // band pair (2s, 2s+1) -> bin row i8 = 2*i4 + s
        const int i8 = 2 * i4 + s;
        const int j8 = 2 * j4;
        vf4 bin0 = vmax(ls0[2 * s][c4i], ls0[2 * s + 1][c4i]);
        vf4 bin1 = vmax(ls1[2 * s][c4i], ls1[2 * s + 1][c4i]);
        __builtin_nontemporal_store(bin0,
            reinterpret_cast<vf4*>(row + S8_OFF + (i8 * 8 + j8) * 512) + c4g);
        __builtin_nontemporal_store(bin1,
            reinterpret_cast<vf4*>(row + S8_OFF + (i8 * 8 + j8 + 1) * 512) + c4g);
        ls0[s][c4i] = vmax(bin0, bin1);    // s4 partial
    }
    __syncthreads();
    if (s == 0) {
        vf4 v4 = vmax(ls0[0][c4i], ls0[1][c4i]);
        reinterpret_cast<vf4*>(row + S4_OFF + (i4 * 4 + j4) * 512)[c4g] = v4;

        // publish into s2 / s1 via fmax lattice atomics (4 resp. 16 writers
        // per address, channel-disjoint across chalf)
        const int q = (i4 >> 1) * 2 + (j4 >> 1);
        float* s2p = row + S2_OFF + q * 512 + c4g * 4;
        float* s1p = row + c4g * 4;
        atomicFmax(s2p + 0, v4.x);
        atomicFmax(s2p + 1, v4.y);
        atomicFmax(s2p + 2, v4.z);
        atomicFmax(s2p + 3, v4.w);
        atomicFmax(s1p + 0, v4.x);
        atomicFmax(s1p + 1, v4.y);
        atomicFmax(s1p + 2, v4.z);
        atomicFmax(s1p + 3, v4.w);
    }
}

extern "C" void kernel_launch(void* const* d_in, const int* in_sizes, int n_in,
                              void* d_out, int out_size, void* d_ws, size_t ws_size,
                              hipStream_t stream) {
    const float* x = (const float*)d_in[0];
    float* out = (float*)d_out;

    spp_fused<<<1024, 256, 0, stream>>>(x, out);
}

// Round 8
// 46.068 us; speedup vs baseline: 1.0168x; 1.0168x over previous
//
#include <hip/hip_runtime.h>
#include <hip/hip_bf16.h>
#include <math.h>

// SPP max-pool pyramid: x [B=32, H=64, W=64, C=512] f32 (NHWC, C innermost)
// scales (1,1),(2,2),(4,4),(8,8). Output row layout per batch (43520 floats):
//   [0,512)        : 1x1 scale
//   [512,2560)     : 2x2 scale, (i2*2+j2)*512 + c
//   [2560,10752)   : 4x4 scale, (i4*4+j4)*512 + c
//   [10752,43520)  : 8x8 scale, (i8*8+j8)*512 + c
// All bin sizes divide 64 evenly, so uniform bins (last-bin-extends is a no-op).
//
// Two dispatches. Single-kernel fusion attempts both regressed:
//   R4 ticket+threadfence: 131us (agent-release forces per-XCD L2 writeback)
//   R7 fmax-lattice atomics: 46.8us (512K device-scope atomics mid-stream)
// R8: occupancy probe 16 -> 32 waves/CU (R5->R6's 8->16 gave -1.6us).
// Kernel 1 split by channel-QUARTER: 2048 blocks x 256 threads.

#define C_F4 128          // 512 channels / 4
#define ROW_OUT 43520     // 85 * 512
#define S8_OFF 10752
#define S4_OFF 2560
#define S2_OFF 512

typedef float vf4 __attribute__((ext_vector_type(4)));

static __device__ __forceinline__ vf4 vmax(vf4 a, vf4 b) {
    vf4 r;
    r.x = fmaxf(a.x, b.x);
    r.y = fmaxf(a.y, b.y);
    r.z = fmaxf(a.z, b.z);
    r.w = fmaxf(a.w, b.w);
    return r;
}

// Kernel 1: one block per (b, i4, j4, cq) = 2048 blocks x 256 threads.
// cq = channel quarter (32 f4 slots = 128 channels). Thread = (s in 0..7:
// 2-row band of the 16-row patch, c4i in 0..31). Each thread: 32 loads ->
// two w-bin partials (cols 0..7 / 8..15 of the patch); LDS tree combines
// 4-band groups into the four s8 bins (2x2) and then the s4 bin.
__global__ __launch_bounds__(256) void spp_pool84(const float* __restrict__ x,
                                                  float* __restrict__ out) {
    const int blk = blockIdx.x;            // 0..2047
    const int b   = blk >> 6;
    const int rem = blk & 63;
    const int i4  = rem >> 4;
    const int j4  = (rem >> 2) & 3;
    const int cq  = rem & 3;
    const int tid = threadIdx.x;           // 0..255
    const int s   = tid >> 5;              // band 0..7 (rows 2s..2s+1)
    const int c4i = tid & 31;
    const int c4g = cq * 32 + c4i;         // global f4 channel slot 0..127

    const int row0 = i4 * 16 + s * 2;
    const vf4* src = reinterpret_cast<const vf4*>(x)
                   + (size_t)((b * 64 + row0) * 64 + j4 * 16) * C_F4 + c4g;
    // vf4 strides: next col = 128, next row = 64*128 = 8192

    vf4 m0 = src[0];            // cols 0..7  (j8 = 2*j4)
    vf4 m1 = src[8 * 128];      // cols 8..15 (j8 = 2*j4+1)
    #pragma unroll
    for (int dr = 0; dr < 2; ++dr) {
        #pragma unroll
        for (int w = 0; w < 8; ++w) {
            if (dr == 0 && w == 0) continue;
            m0 = vmax(m0, src[dr * 8192 + w * 128]);
            m1 = vmax(m1, src[dr * 8192 + (w + 8) * 128]);
        }
    }

    __shared__ vf4 ls0[8][32];
    __shared__ vf4 ls1[8][32];
    ls0[s][c4i] = m0;
    ls1[s][c4i] = m1;
    __syncthreads();

    float* row = out + (size_t)b * ROW_OUT;
    if (s < 2) {
        // band group 4s..4s+3 -> bin row i8 = 2*i4 + s
        const int i8 = 2 * i4 + s;
        const int j8 = 2 * j4;
        vf4 bin0 = vmax(vmax(ls0[4 * s][c4i],     ls0[4 * s + 1][c4i]),
                        vmax(ls0[4 * s + 2][c4i], ls0[4 * s + 3][c4i]));
        vf4 bin1 = vmax(vmax(ls1[4 * s][c4i],     ls1[4 * s + 1][c4i]),
                        vmax(ls1[4 * s + 2][c4i], ls1[4 * s + 3][c4i]));
        __builtin_nontemporal_store(bin0,
            reinterpret_cast<vf4*>(row + S8_OFF + (i8 * 8 + j8) * 512) + c4g);
        __builtin_nontemporal_store(bin1,
            reinterpret_cast<vf4*>(row + S8_OFF + (i8 * 8 + j8 + 1) * 512) + c4g);
        ls0[s][c4i] = vmax(bin0, bin1);    // s4 partial
    }
    __syncthreads();
    if (s == 0) {
        vf4 v4 = vmax(ls0[0][c4i], ls0[1][c4i]);
        reinterpret_cast<vf4*>(row + S4_OFF + (i4 * 4 + j4) * 512)[c4g] = v4;
    }
}

// Kernel 2: derive 2x2 / 1x1 from the 4x4 scale (1 MB, cache-hot).
// One block per batch, 512 threads = (quadrant q, c4); 4 loads per thread.
__global__ __launch_bounds__(512) void spp_tail(float* __restrict__ out) {
    const int b   = blockIdx.x;           // 0..31
    const int tid = threadIdx.x;          // 0..511
    const int q   = tid >> 7;             // quadrant 0..3
    const int c4  = tid & 127;
    const int i2  = q >> 1;
    const int j2  = q & 1;

    float* row = out + (size_t)b * ROW_OUT;
    const vf4* p4 = reinterpret_cast<const vf4*>(row + S4_OFF) + c4;

    vf4 m =     p4[((2 * i2)     * 4 + 2 * j2)     * C_F4];
    m = vmax(m, p4[((2 * i2)     * 4 + 2 * j2 + 1) * C_F4]);
    m = vmax(m, p4[((2 * i2 + 1) * 4 + 2 * j2)     * C_F4]);
    m = vmax(m, p4[((2 * i2 + 1) * 4 + 2 * j2 + 1) * C_F4]);

    reinterpret_cast<vf4*>(row + S2_OFF + q * 512)[c4] = m;

    __shared__ vf4 ls[4][128];
    ls[q][c4] = m;
    __syncthreads();
    if (q == 0) {
        vf4 v1 = vmax(vmax(ls[0][c4], ls[1][c4]),
                      vmax(ls[2][c4], ls[3][c4]));
        reinterpret_cast<vf4*>(row)[c4] = v1;
    }
}

extern "C" void kernel_launch(void* const* d_in, const int* in_sizes, int n_in,
                              void* d_out, int out_size, void* d_ws, size_t ws_size,
                              hipStream_t stream) {
    const float* x = (const float*)d_in[0];
    float* out = (float*)d_out;

    spp_pool84<<<2048, 256, 0, stream>>>(x, out);
    spp_tail<<<32, 512, 0, stream>>>(out);
}